// Round 1
// baseline (374.828 us; speedup 1.0000x reference)
//
#include <hip/hip_runtime.h>

#define NN 100000
#define EE 400000

typedef unsigned short u16;
typedef unsigned int u32;
typedef short short8 __attribute__((ext_vector_type(8)));
typedef __bf16 bf16x8 __attribute__((ext_vector_type(8)));
typedef float f32x4 __attribute__((ext_vector_type(4)));

__device__ __forceinline__ short8 pack_bf16x8(f32x4 lo, f32x4 hi) {
  bf16x8 r;
#pragma unroll
  for (int j = 0; j < 4; ++j) { r[j] = (__bf16)lo[j]; r[4 + j] = (__bf16)hi[j]; }
  return __builtin_bit_cast(short8, r);
}

__device__ __forceinline__ u16 f2bf(float f) {
  return __builtin_bit_cast(unsigned short, (__bf16)f);
}

// ---------------------------------------------------------------------------
// K1: per-edge MLP  h = relu(LN(concat(x[row], ea) @ W1 + b1)) ; atomic scatter
// into agg[col].  WG = 256 thr (4 waves), 128 edges/WG, 32 edges/wave.
// W1^T staged in 64KB LDS, XOR-swizzled, bf16.
// ---------------------------------------------------------------------------
__global__ void __launch_bounds__(256) k_edge(
    const float* __restrict__ x, const float* __restrict__ ea,
    const float* __restrict__ W1, const float* __restrict__ b1,
    const float* __restrict__ g1, const float* __restrict__ be1,
    const int* __restrict__ eidx, float* __restrict__ agg)
{
  extern __shared__ char smem[];  // 65536 B: Wt[n=0..127][k=0..255] bf16, swizzled
  const int tid = threadIdx.x;
#pragma unroll 4
  for (int it = 0; it < 32; ++it) {
    int idx = it * 256 + tid;          // 0..8191
    int k = idx >> 5;                  // 0..255
    int ng = (idx & 31) * 4;           // n group
    f32x4 w = *reinterpret_cast<const f32x4*>(W1 + k * 128 + ng);
#pragma unroll
    for (int j = 0; j < 4; ++j) {
      int n = ng + j;
      int off = n * 512 + ((2 * k) ^ ((n & 7) << 4));
      *reinterpret_cast<u16*>(smem + off) = f2bf(w[j]);
    }
  }
  __syncthreads();

  const int lane = tid & 63;
  const int wv = tid >> 6;
  const int lo = lane & 15;
  const int kb = lane >> 4;
  const long ebase = (long)blockIdx.x * 128 + wv * 32;

  // A fragments: 2 m-tiles x 8 k-chunks, packed f32->bf16
  short8 a[2][8];
#pragma unroll
  for (int mt = 0; mt < 2; ++mt) {
    long e = ebase + mt * 16 + lo;
    long r = eidx[e];
#pragma unroll
    for (int kc = 0; kc < 8; ++kc) {
      int k = kc * 32 + kb * 8;
      const float* src = (k < 128) ? (x + r * 128 + k) : (ea + e * 128 + (k - 128));
      f32x4 v0 = *reinterpret_cast<const f32x4*>(src);
      f32x4 v1 = *reinterpret_cast<const f32x4*>(src + 4);
      a[mt][kc] = pack_bf16x8(v0, v1);
    }
  }

  f32x4 acc[2][8];
#pragma unroll
  for (int mt = 0; mt < 2; ++mt)
#pragma unroll
    for (int nt = 0; nt < 8; ++nt)
      acc[mt][nt] = (f32x4){0.f, 0.f, 0.f, 0.f};

#pragma unroll
  for (int nt = 0; nt < 8; ++nt) {
    int n = nt * 16 + lo;
    int rowoff = n * 512;
    int sw = (n & 7) << 4;
#pragma unroll
    for (int kc = 0; kc < 8; ++kc) {
      short8 b = *reinterpret_cast<const short8*>(smem + rowoff + ((2 * (kc * 32 + kb * 8)) ^ sw));
      acc[0][nt] = __builtin_amdgcn_mfma_f32_16x16x32_bf16(a[0][kc], b, acc[0][nt], 0, 0, 0);
      acc[1][nt] = __builtin_amdgcn_mfma_f32_16x16x32_bf16(a[1][kc], b, acc[1][nt], 0, 0, 0);
    }
  }

  float b1v[8], g1v[8], bev[8];
#pragma unroll
  for (int nt = 0; nt < 8; ++nt) {
    int c = nt * 16 + lo;
    b1v[nt] = b1[c]; g1v[nt] = g1[c]; bev[nt] = be1[c];
  }

#pragma unroll
  for (int mt = 0; mt < 2; ++mt) {
    float s[4] = {0.f, 0.f, 0.f, 0.f};
    float q[4] = {0.f, 0.f, 0.f, 0.f};
#pragma unroll
    for (int nt = 0; nt < 8; ++nt)
#pragma unroll
      for (int i = 0; i < 4; ++i) {
        float v = acc[mt][nt][i] + b1v[nt];
        acc[mt][nt][i] = v;
        s[i] += v; q[i] += v * v;
      }
#pragma unroll
    for (int m = 1; m < 16; m <<= 1)
#pragma unroll
      for (int i = 0; i < 4; ++i) {
        s[i] += __shfl_xor(s[i], m);
        q[i] += __shfl_xor(q[i], m);
      }
    float mu[4], rs[4];
    int cols[4];
#pragma unroll
    for (int i = 0; i < 4; ++i) {
      mu[i] = s[i] * (1.f / 128.f);
      float var = q[i] * (1.f / 128.f) - mu[i] * mu[i];
      rs[i] = rsqrtf(var + 1e-5f);
      cols[i] = eidx[EE + ebase + mt * 16 + kb * 4 + i];
    }
#pragma unroll
    for (int nt = 0; nt < 8; ++nt)
#pragma unroll
      for (int i = 0; i < 4; ++i) {
        float v = fmaxf((acc[mt][nt][i] - mu[i]) * rs[i] * g1v[nt] + bev[nt], 0.f);
        atomicAdd(agg + (long)cols[i] * 128 + nt * 16 + lo, v);
      }
  }
}

// ---------------------------------------------------------------------------
// K2a: u = (1+eps)*x + agg ; t1 = relu(LN(u @ W2 + b2)) stored bf16
// ---------------------------------------------------------------------------
__global__ void __launch_bounds__(256) k_node1(
    const float* __restrict__ x, const float* __restrict__ agg,
    const float* __restrict__ W2, const float* __restrict__ b2,
    const float* __restrict__ g2, const float* __restrict__ be2,
    const float* __restrict__ epsp, u16* __restrict__ t1)
{
  __shared__ char smem[32768];  // W2^T bf16 swizzled [n=0..127][k=0..127]
  const int tid = threadIdx.x;
#pragma unroll 4
  for (int it = 0; it < 16; ++it) {
    int idx = it * 256 + tid;          // 0..4095
    int k = idx >> 5;                  // 0..127
    int ng = (idx & 31) * 4;
    f32x4 w = *reinterpret_cast<const f32x4*>(W2 + k * 128 + ng);
#pragma unroll
    for (int j = 0; j < 4; ++j) {
      int n = ng + j;
      *reinterpret_cast<u16*>(smem + n * 256 + ((2 * k) ^ ((n & 7) << 4))) = f2bf(w[j]);
    }
  }
  __syncthreads();

  const int lane = tid & 63, wv = tid >> 6, lo = lane & 15, kb = lane >> 4;
  const long rb = (long)blockIdx.x * 128 + wv * 32;
  const float ope = 1.f + epsp[0];

  short8 a[2][4];
#pragma unroll
  for (int mt = 0; mt < 2; ++mt) {
    long row = rb + mt * 16 + lo;
    long rc = row < NN ? row : (NN - 1);
#pragma unroll
    for (int kc = 0; kc < 4; ++kc) {
      int k = kc * 32 + kb * 8;
      f32x4 x0 = *reinterpret_cast<const f32x4*>(x + rc * 128 + k);
      f32x4 x1 = *reinterpret_cast<const f32x4*>(x + rc * 128 + k + 4);
      f32x4 a0 = *reinterpret_cast<const f32x4*>(agg + rc * 128 + k);
      f32x4 a1 = *reinterpret_cast<const f32x4*>(agg + rc * 128 + k + 4);
      f32x4 u0, u1;
#pragma unroll
      for (int j = 0; j < 4; ++j) {
        u0[j] = fmaf(x0[j], ope, a0[j]);
        u1[j] = fmaf(x1[j], ope, a1[j]);
      }
      a[mt][kc] = pack_bf16x8(u0, u1);
    }
  }

  f32x4 acc[2][8];
#pragma unroll
  for (int mt = 0; mt < 2; ++mt)
#pragma unroll
    for (int nt = 0; nt < 8; ++nt)
      acc[mt][nt] = (f32x4){0.f, 0.f, 0.f, 0.f};

#pragma unroll
  for (int nt = 0; nt < 8; ++nt) {
    int n = nt * 16 + lo;
    int rowoff = n * 256;
    int sw = (n & 7) << 4;
#pragma unroll
    for (int kc = 0; kc < 4; ++kc) {
      short8 b = *reinterpret_cast<const short8*>(smem + rowoff + ((2 * (kc * 32 + kb * 8)) ^ sw));
      acc[0][nt] = __builtin_amdgcn_mfma_f32_16x16x32_bf16(a[0][kc], b, acc[0][nt], 0, 0, 0);
      acc[1][nt] = __builtin_amdgcn_mfma_f32_16x16x32_bf16(a[1][kc], b, acc[1][nt], 0, 0, 0);
    }
  }

  float b2v[8], g2v[8], bev[8];
#pragma unroll
  for (int nt = 0; nt < 8; ++nt) {
    int c = nt * 16 + lo;
    b2v[nt] = b2[c]; g2v[nt] = g2[c]; bev[nt] = be2[c];
  }

#pragma unroll
  for (int mt = 0; mt < 2; ++mt) {
    float s[4] = {0.f, 0.f, 0.f, 0.f};
    float q[4] = {0.f, 0.f, 0.f, 0.f};
#pragma unroll
    for (int nt = 0; nt < 8; ++nt)
#pragma unroll
      for (int i = 0; i < 4; ++i) {
        float v = acc[mt][nt][i] + b2v[nt];
        acc[mt][nt][i] = v;
        s[i] += v; q[i] += v * v;
      }
#pragma unroll
    for (int m = 1; m < 16; m <<= 1)
#pragma unroll
      for (int i = 0; i < 4; ++i) {
        s[i] += __shfl_xor(s[i], m);
        q[i] += __shfl_xor(q[i], m);
      }
    float mu[4], rs[4];
    long rows[4];
#pragma unroll
    for (int i = 0; i < 4; ++i) {
      mu[i] = s[i] * (1.f / 128.f);
      float var = q[i] * (1.f / 128.f) - mu[i] * mu[i];
      rs[i] = rsqrtf(var + 1e-5f);
      rows[i] = rb + mt * 16 + kb * 4 + i;
    }
#pragma unroll
    for (int nt = 0; nt < 8; ++nt)
#pragma unroll
      for (int i = 0; i < 4; ++i) {
        float v = fmaxf((acc[mt][nt][i] - mu[i]) * rs[i] * g2v[nt] + bev[nt], 0.f);
        float vn = __shfl_xor(v, 1);
        if (!(lo & 1) && rows[i] < NN) {
          u32 pk = (u32)f2bf(v) | ((u32)f2bf(vn) << 16);
          *reinterpret_cast<u32*>(t1 + rows[i] * 128 + nt * 16 + lo) = pk;
        }
      }
  }
}

// ---------------------------------------------------------------------------
// K2b: pre = t1 @ W3 + b3 + 2*x ; store f32 + per-WG column partial sums
// ---------------------------------------------------------------------------
__global__ void __launch_bounds__(256) k_node2(
    const u16* __restrict__ t1, const float* __restrict__ x,
    const float* __restrict__ W3, const float* __restrict__ b3,
    float* __restrict__ tmp, float* __restrict__ part)
{
  __shared__ char smem[32768];  // W3^T bf16 swizzled
  const int tid = threadIdx.x;
#pragma unroll 4
  for (int it = 0; it < 16; ++it) {
    int idx = it * 256 + tid;
    int k = idx >> 5;
    int ng = (idx & 31) * 4;
    f32x4 w = *reinterpret_cast<const f32x4*>(W3 + k * 128 + ng);
#pragma unroll
    for (int j = 0; j < 4; ++j) {
      int n = ng + j;
      *reinterpret_cast<u16*>(smem + n * 256 + ((2 * k) ^ ((n & 7) << 4))) = f2bf(w[j]);
    }
  }
  __syncthreads();

  const int lane = tid & 63, wv = tid >> 6, lo = lane & 15, kb = lane >> 4;
  const long rb = (long)blockIdx.x * 128 + wv * 32;

  short8 a[2][4];
#pragma unroll
  for (int mt = 0; mt < 2; ++mt) {
    long row = rb + mt * 16 + lo;
    long rc = row < NN ? row : (NN - 1);
#pragma unroll
    for (int kc = 0; kc < 4; ++kc)
      a[mt][kc] = *reinterpret_cast<const short8*>(t1 + rc * 128 + kc * 32 + kb * 8);
  }

  f32x4 acc[2][8];
#pragma unroll
  for (int mt = 0; mt < 2; ++mt)
#pragma unroll
    for (int nt = 0; nt < 8; ++nt)
      acc[mt][nt] = (f32x4){0.f, 0.f, 0.f, 0.f};

#pragma unroll
  for (int nt = 0; nt < 8; ++nt) {
    int n = nt * 16 + lo;
    int rowoff = n * 256;
    int sw = (n & 7) << 4;
#pragma unroll
    for (int kc = 0; kc < 4; ++kc) {
      short8 b = *reinterpret_cast<const short8*>(smem + rowoff + ((2 * (kc * 32 + kb * 8)) ^ sw));
      acc[0][nt] = __builtin_amdgcn_mfma_f32_16x16x32_bf16(a[0][kc], b, acc[0][nt], 0, 0, 0);
      acc[1][nt] = __builtin_amdgcn_mfma_f32_16x16x32_bf16(a[1][kc], b, acc[1][nt], 0, 0, 0);
    }
  }

  float b3v[8];
#pragma unroll
  for (int nt = 0; nt < 8; ++nt) b3v[nt] = b3[nt * 16 + lo];

  float sn[8] = {0.f, 0.f, 0.f, 0.f, 0.f, 0.f, 0.f, 0.f};
  float qn[8] = {0.f, 0.f, 0.f, 0.f, 0.f, 0.f, 0.f, 0.f};

#pragma unroll
  for (int mt = 0; mt < 2; ++mt) {
    long rows[4], rc[4];
    bool val[4];
#pragma unroll
    for (int i = 0; i < 4; ++i) {
      rows[i] = rb + mt * 16 + kb * 4 + i;
      val[i] = rows[i] < NN;
      rc[i] = val[i] ? rows[i] : (NN - 1);
    }
#pragma unroll
    for (int nt = 0; nt < 8; ++nt)
#pragma unroll
      for (int i = 0; i < 4; ++i) {
        float v = acc[mt][nt][i] + b3v[nt] + 2.f * x[rc[i] * 128 + nt * 16 + lo];
        if (val[i]) {
          tmp[rows[i] * 128 + nt * 16 + lo] = v;
          sn[nt] += v; qn[nt] += v * v;
        }
      }
  }
#pragma unroll
  for (int nt = 0; nt < 8; ++nt) {
    sn[nt] += __shfl_xor(sn[nt], 16); sn[nt] += __shfl_xor(sn[nt], 32);
    qn[nt] += __shfl_xor(qn[nt], 16); qn[nt] += __shfl_xor(qn[nt], 32);
  }
  if (lane < 16) {
    long pr = ((long)blockIdx.x * 4 + wv) * 256;
#pragma unroll
    for (int nt = 0; nt < 8; ++nt) {
      part[pr + nt * 16 + lane] = sn[nt];
      part[pr + 128 + nt * 16 + lane] = qn[nt];
    }
  }
}

// ---------------------------------------------------------------------------
// K2c: reduce partials -> per-column scale/shift for BN
// ---------------------------------------------------------------------------
__global__ void __launch_bounds__(256) k_stats(
    const float* __restrict__ part, const float* __restrict__ bng,
    const float* __restrict__ bnb, float* __restrict__ stats2)
{
  const int c = blockIdx.x;        // 0..127
  const int tid = threadIdx.x;
  float s = 0.f, q = 0.f;
  for (int i = tid; i < 3128; i += 256) {
    s += part[(long)i * 256 + c];
    q += part[(long)i * 256 + 128 + c];
  }
#pragma unroll
  for (int m = 1; m < 64; m <<= 1) { s += __shfl_xor(s, m); q += __shfl_xor(q, m); }
  __shared__ float rs_[4], rq_[4];
  const int wv = tid >> 6;
  if ((tid & 63) == 0) { rs_[wv] = s; rq_[wv] = q; }
  __syncthreads();
  if (tid == 0) {
    s = rs_[0] + rs_[1] + rs_[2] + rs_[3];
    q = rq_[0] + rq_[1] + rq_[2] + rq_[3];
    float mu = s * (1.f / (float)NN);
    float var = q * (1.f / (float)NN) - mu * mu;
    float sc = rsqrtf(var + 1e-5f) * bng[c];
    stats2[c] = sc;
    stats2[128 + c] = bnb[c] - mu * sc;
  }
}

// ---------------------------------------------------------------------------
// K3: BN apply, f32 out
// ---------------------------------------------------------------------------
__global__ void __launch_bounds__(256) k_apply(
    const float* __restrict__ tmp, const float* __restrict__ stats2,
    float* __restrict__ out)
{
  const long total = (long)NN * 32;  // vec4 count
  for (long i = (long)blockIdx.x * 256 + threadIdx.x; i < total;
       i += (long)gridDim.x * 256) {
    int db = (int)((i & 31) << 2);
    f32x4 v = reinterpret_cast<const f32x4*>(tmp)[i];
    f32x4 sc = *reinterpret_cast<const f32x4*>(stats2 + db);
    f32x4 sh = *reinterpret_cast<const f32x4*>(stats2 + 128 + db);
    f32x4 o;
#pragma unroll
    for (int j = 0; j < 4; ++j) o[j] = fmaf(v[j], sc[j], sh[j]);
    reinterpret_cast<f32x4*>(out)[i] = o;
  }
}

extern "C" void kernel_launch(void* const* d_in, const int* in_sizes, int n_in,
                              void* d_out, int out_size, void* d_ws, size_t ws_size,
                              hipStream_t stream)
{
  const float* x   = (const float*)d_in[0];
  const float* ea  = (const float*)d_in[1];
  const float* W1  = (const float*)d_in[2];
  const float* b1  = (const float*)d_in[3];
  const float* g1  = (const float*)d_in[4];
  const float* be1 = (const float*)d_in[5];
  const float* W2  = (const float*)d_in[6];
  const float* b2  = (const float*)d_in[7];
  const float* g2  = (const float*)d_in[8];
  const float* be2 = (const float*)d_in[9];
  const float* W3  = (const float*)d_in[10];
  const float* b3  = (const float*)d_in[11];
  const float* eps = (const float*)d_in[12];
  const float* bng = (const float*)d_in[13];
  const float* bnb = (const float*)d_in[14];
  const int*   eidx = (const int*)d_in[15];
  float* out = (float*)d_out;

  float* agg    = (float*)d_ws;                  // N*128 f32
  float* tmp    = agg;                           // alias: agg dead after k_node1
  float* part   = agg + (long)NN * 128;          // 3128*256 f32
  float* stats2 = part + 3128L * 256;            // 256 f32
  u16*   t1     = (u16*)(stats2 + 256);          // N*128 bf16

  hipMemsetAsync(agg, 0, (size_t)NN * 128 * 4, stream);
  k_edge  <<<EE / 128, 256, 65536, stream>>>(x, ea, W1, b1, g1, be1, eidx, agg);
  k_node1 <<<(NN + 127) / 128, 256, 0, stream>>>(x, agg, W2, b2, g2, be2, eps, t1);
  k_node2 <<<(NN + 127) / 128, 256, 0, stream>>>(t1, x, W3, b3, tmp, part);
  k_stats <<<128, 256, 0, stream>>>(part, bng, bnb, stats2);
  k_apply <<<2048, 256, 0, stream>>>(tmp, stats2, out);
}